// Round 3
// baseline (2420.924 us; speedup 1.0000x reference)
//
#include <hip/hip_runtime.h>
#include <hip/hip_bf16.h>
#include <math.h>

// ---------------------------------------------------------------------------
// Fused linear cross-entropy:  hidden(2047x2048) @ W^T(151936x2048) -> LSE - tgt
// Round 3: 256x256 tile, BK=32, 3-buffer LDS ring, 4-phase K-tile schedule
// with counted vmcnt(4) (T3+T4), setprio around MFMA (T5), T2 chunk swizzle,
// XCD-bijective block swizzle (T1). N padded to 152064, masked in epilogue.
// ---------------------------------------------------------------------------

#define V_SIZE   151936
#define V_PAD    152064    // 594 * 256
#define H_SIZE   2048
#define M_ROWS   2048      // 2047 real rows + 1 zero pad row
#define M_REAL   2047
#define NB_CNT   594       // 152064 / 256
#define BM 256
#define BN 256
#define BK 32
#define KT_CNT   (H_SIZE / BK)   // 64
#define NBLK (8 * NB_CNT)        // 4752 blocks, divisible by 8
#define IGNORE_INDEX (-100)

typedef short bf16x8 __attribute__((ext_vector_type(8)));
typedef float floatx4 __attribute__((ext_vector_type(4)));

__device__ __forceinline__ unsigned short f2bf_rne(float f) {
    union { float f; unsigned u; } x; x.f = f;
    unsigned r = (x.u + 0x7fffu + ((x.u >> 16) & 1u)) >> 16;
    return (unsigned short)r;
}

__device__ __forceinline__ void gload16(const void* g, void* l) {
    __builtin_amdgcn_global_load_lds(
        (const __attribute__((address_space(1))) unsigned int*)g,
        (__attribute__((address_space(3))) unsigned int*)l, 16, 0, 0);
}

// ---- conversion kernels ----------------------------------------------------

__global__ void cvt_weight(const float4* __restrict__ in,
                           ushort4* __restrict__ out, long n4real, long n4pad) {
    long i = (long)blockIdx.x * blockDim.x + threadIdx.x;
    long stride = (long)gridDim.x * blockDim.x;
    for (; i < n4pad; i += stride) {
        ushort4 o;
        if (i < n4real) {
            float4 v = in[i];
            o.x = f2bf_rne(v.x); o.y = f2bf_rne(v.y);
            o.z = f2bf_rne(v.z); o.w = f2bf_rne(v.w);
        } else {
            o.x = 0; o.y = 0; o.z = 0; o.w = 0;
        }
        out[i] = o;
    }
}

__global__ void cvt_hidden(const float4* __restrict__ in,
                           ushort4* __restrict__ out) {
    const long n4 = (long)M_ROWS * H_SIZE / 4;
    const long valid4 = (long)M_REAL * H_SIZE / 4;
    long i = (long)blockIdx.x * blockDim.x + threadIdx.x;
    long stride = (long)gridDim.x * blockDim.x;
    for (; i < n4; i += stride) {
        ushort4 o;
        if (i < valid4) {
            float4 v = in[i];
            o.x = f2bf_rne(v.x); o.y = f2bf_rne(v.y);
            o.z = f2bf_rne(v.z); o.w = f2bf_rne(v.w);
        } else {
            o.x = 0; o.y = 0; o.z = 0; o.w = 0;
        }
        out[i] = o;
    }
}

// ---- main GEMM + per-tile online-LSE epilogue ------------------------------
// 512 threads (8 waves, 2M x 4N). Per-wave output 128x64 = acc[8][4] 16x16
// frags. 3-deep LDS ring of (A[256][32] + B[256][32]) K-tiles; per K-tile,
// 4 quadrant phases; stage K-tile k+2 one piece per phase; vmcnt(4)/K-tile.

__global__ __launch_bounds__(512, 2) void gemm_lse(
    const unsigned short* __restrict__ hbf,   // [2048][2048]
    const unsigned short* __restrict__ wbf,   // [152064][2048] (padded)
    float* __restrict__ pmax,                 // [594][2048]
    float* __restrict__ psum) {               // [594][2048]
    __shared__ short lds[3][16384];           // per buf: A at 0, B at 8192 (shorts)
    __shared__ float eM[BM][4];
    __shared__ float eS[BM][4];

    const int t    = threadIdx.x;
    const int lane = t & 63;
    const int w    = t >> 6;
    const int wm   = w >> 2;          // 0..1 -> 128 rows
    const int wn   = w & 3;           // 0..3 -> 64 cols
    const int fr   = lane & 15;
    const int fq   = lane >> 4;       // 0..3, selects 16B k-chunk
    const int ck   = fq ^ ((fr >> 1) & 3);   // swizzled physical chunk

    // XCD-bijective remap: 4752 = 8 * 594
    const int b    = blockIdx.x;
    const int lin  = (b & 7) * (NBLK / 8) + (b >> 3);
    const int mb   = lin & 7;         // 8 m-blocks fast -> weight-slab L2 reuse
    const int nb   = lin >> 3;
    const int m0   = mb * BM;
    const int n0   = nb * BN;

    // staging: thread t covers row (t>>2) of a 128-row half (one issue = 8KB),
    // physical chunk (t&3) <- logical chunk (t&3)^((row>>1)&3) (T2 swizzle,
    // pre-swizzled global source, linear LDS dest).
    const int srow   = t >> 2;
    const int schunk = (t & 3) ^ ((t >> 3) & 3);
    const unsigned short* srcA0 = hbf + (size_t)(m0 + srow) * H_SIZE + schunk * 8;
    const unsigned short* srcA1 = srcA0 + (size_t)128 * H_SIZE;
    const unsigned short* srcB0 = wbf + (size_t)(n0 + srow) * H_SIZE + schunk * 8;
    const unsigned short* srcB1 = srcB0 + (size_t)128 * H_SIZE;

    floatx4 zero4 = {0.f, 0.f, 0.f, 0.f};
    floatx4 acc[8][4];
#pragma unroll
    for (int i = 0; i < 8; ++i)
#pragma unroll
        for (int j = 0; j < 4; ++j) acc[i][j] = zero4;

    // ---- prologue: stage K-tiles 0 and 1 ----
    {
        short* st0 = &lds[0][0];
        short* st1 = &lds[1][0];
        gload16(srcA0,      st0 + 0 * 4096 + t * 8);
        gload16(srcA1,      st0 + 1 * 4096 + t * 8);
        gload16(srcB0,      st0 + 2 * 4096 + t * 8);
        gload16(srcB1,      st0 + 3 * 4096 + t * 8);
        gload16(srcA0 + 32, st1 + 0 * 4096 + t * 8);
        gload16(srcA1 + 32, st1 + 1 * 4096 + t * 8);
        gload16(srcB0 + 32, st1 + 2 * 4096 + t * 8);
        gload16(srcB1 + 32, st1 + 3 * 4096 + t * 8);
    }
    asm volatile("s_waitcnt vmcnt(4)" ::: "memory");   // K0 landed
    __builtin_amdgcn_s_barrier();
    asm volatile("" ::: "memory");

    int bufk = 0, bufs = 2;
    for (int k = 0; k < KT_CNT; ++k) {
        const short* baseA = &lds[bufk][0];
        const short* pA = baseA + (wm * 128 + fr) * 32 + ck * 8;
        const short* pB = baseA + 8192 + (wn * 64 + fr) * 32 + ck * 8;
        short* stBase = &lds[bufs][0];
        const int kof2 = (k + 2) * 32;
        const bool doStage = (k < KT_CNT - 2);

#pragma unroll
        for (int q = 0; q < 4; ++q) {
            // 6 swizzled ds_read_b128 for quadrant q
            bf16x8 af[4], bfv[2];
#pragma unroll
            for (int i = 0; i < 4; ++i)
                af[i] = *(const bf16x8*)(pA + (q >> 1) * 2048 + i * 512);
#pragma unroll
            for (int j = 0; j < 2; ++j)
                bfv[j] = *(const bf16x8*)(pB + (q & 1) * 1024 + j * 512);

            // stage one 8KB piece of K-tile k+2 (A0,A1,B0,B1 across phases)
            if (doStage) {
                const unsigned short* s = (q == 0) ? srcA0 : (q == 1) ? srcA1
                                        : (q == 2) ? srcB0 : srcB1;
                gload16(s + kof2, stBase + q * 4096 + t * 8);
            }

            asm volatile("" ::: "memory");
            __builtin_amdgcn_s_barrier();
            asm volatile("s_waitcnt lgkmcnt(0)" ::: "memory");
            __builtin_amdgcn_sched_barrier(0);
            __builtin_amdgcn_s_setprio(1);
#pragma unroll
            for (int i = 0; i < 4; ++i)
#pragma unroll
                for (int j = 0; j < 2; ++j)
                    acc[(q >> 1) * 4 + i][(q & 1) * 2 + j] =
                        __builtin_amdgcn_mfma_f32_16x16x32_bf16(
                            af[i], bfv[j],
                            acc[(q >> 1) * 4 + i][(q & 1) * 2 + j], 0, 0, 0);
            __builtin_amdgcn_s_setprio(0);
            __builtin_amdgcn_sched_barrier(0);

            if (q == 3) {   // K-tile boundary: counted drain (never 0 mid-loop)
                if (k < KT_CNT - 2) {
                    asm volatile("s_waitcnt vmcnt(4)" ::: "memory");
                } else if (k == KT_CNT - 2) {
                    asm volatile("s_waitcnt vmcnt(0)" ::: "memory");
                }
            }
            asm volatile("" ::: "memory");
            __builtin_amdgcn_s_barrier();
            asm volatile("" ::: "memory");
        }
        bufk = (bufk == 2) ? 0 : bufk + 1;
        bufs = (bufs == 2) ? 0 : bufs + 1;
    }

    // ---- epilogue: per-row max + sum(exp) over 256 cols, masked past V ----
    // C/D layout: col = fr, row-in-frag = fq*4 + r.
    const int c0 = n0 + wn * 64 + fr;
#pragma unroll
    for (int m = 0; m < 8; ++m) {
#pragma unroll
        for (int r = 0; r < 4; ++r) {
            float v = -INFINITY;
#pragma unroll
            for (int n = 0; n < 4; ++n)
                if (c0 + n * 16 < V_SIZE) v = fmaxf(v, acc[m][n][r]);
            for (int off = 1; off < 16; off <<= 1)
                v = fmaxf(v, __shfl_xor(v, off, 64));
            float s = 0.f;
#pragma unroll
            for (int n = 0; n < 4; ++n)
                if (c0 + n * 16 < V_SIZE) s += expf(acc[m][n][r] - v);
            for (int off = 1; off < 16; off <<= 1)
                s += __shfl_xor(s, off, 64);
            if (fr == 0) {
                int row = wm * 128 + m * 16 + fq * 4 + r;
                eM[row][wn] = v;
                eS[row][wn] = s;
            }
        }
    }
    __syncthreads();
    if (t < BM) {
        float Mx = eM[t][0];
        for (int i = 1; i < 4; ++i) Mx = fmaxf(Mx, eM[t][i]);
        float Sx = 0.f;
        for (int i = 0; i < 4; ++i) {
            float d = eM[t][i] - Mx;   // -inf - finite -> -inf, exp -> 0
            Sx += eS[t][i] * expf(d);
        }
        size_t grow = (size_t)m0 + t;
        pmax[(size_t)nb * M_ROWS + grow] = Mx;
        psum[(size_t)nb * M_ROWS + grow] = Sx;
    }
}

// ---- per-row reduction: combine partials + exact fp32 target dot -----------

__global__ void zero_acc(float* a) {
    if (threadIdx.x < 2) a[threadIdx.x] = 0.f;
}

__global__ __launch_bounds__(256) void reduce_rows(
    const float* __restrict__ hid,
    const int* __restrict__ labels,
    const float* __restrict__ wt,
    const float* __restrict__ pmax,
    const float* __restrict__ psum,
    float* __restrict__ accum) {
    const int m = blockIdx.x;           // 0..2046
    const int t = threadIdx.x;
    const int lbl = labels[m + 1];
    const bool valid = (lbl != IGNORE_INDEX);

    float dot = 0.f;
    if (valid) {
        int li = lbl < 0 ? 0 : lbl;
        const float4* hr = (const float4*)(hid + (size_t)m * H_SIZE);
        const float4* wr = (const float4*)(wt + (size_t)li * H_SIZE);
#pragma unroll
        for (int i = 0; i < 2; ++i) {
            float4 a = hr[t + i * 256];
            float4 b = wr[t + i * 256];
            dot += a.x * b.x + a.y * b.y + a.z * b.z + a.w * b.w;
        }
    }

    float M = -INFINITY, S = 0.f;
    for (int nbi = t; nbi < NB_CNT; nbi += 256) {
        float m2 = pmax[(size_t)nbi * M_ROWS + m];
        float s2 = psum[(size_t)nbi * M_ROWS + m];
        if (m2 > M) { S = S * expf(M - m2) + s2; M = m2; }
        else        { S += s2 * expf(m2 - M); }
    }
    for (int off = 1; off < 64; off <<= 1) {
        float M2 = __shfl_xor(M, off, 64);
        float S2 = __shfl_xor(S, off, 64);
        float nm = fmaxf(M, M2);
        S = S * expf(M - nm) + S2 * expf(M2 - nm);
        M = nm;
        dot += __shfl_xor(dot, off, 64);
    }
    __shared__ float rM[4], rS[4], rD[4];
    const int wv = t >> 6, lane = t & 63;
    if (lane == 0) { rM[wv] = M; rS[wv] = S; rD[wv] = dot; }
    __syncthreads();
    if (t == 0) {
        float Mx = rM[0], Sx = rS[0], D = rD[0];
        for (int i = 1; i < 4; ++i) {
            float nm = fmaxf(Mx, rM[i]);
            Sx = Sx * expf(Mx - nm) + rS[i] * expf(rM[i] - nm);
            Mx = nm;
            D += rD[i];
        }
        if (valid) {
            atomicAdd(&accum[0], (Mx + logf(Sx)) - D);
            atomicAdd(&accum[1], 1.0f);
        }
    }
}

__global__ void finalize(const float* __restrict__ accum, float* __restrict__ out) {
    out[0] = accum[0] / accum[1];
}

__global__ void sentinel(float* out) { out[0] = -12345.0f; }

// ---------------------------------------------------------------------------

extern "C" void kernel_launch(void* const* d_in, const int* in_sizes, int n_in,
                              void* d_out, int out_size, void* d_ws, size_t ws_size,
                              hipStream_t stream) {
    const float* hid    = (const float*)d_in[0];
    const int*   labels = (const int*)d_in[1];
    const float* wt     = (const float*)d_in[2];
    float* out = (float*)d_out;

    const size_t wbf_bytes  = (size_t)V_PAD * H_SIZE * 2;      // 622,854,144
    const size_t hbf_bytes  = (size_t)M_ROWS * H_SIZE * 2;     //   8,388,608
    const size_t part_bytes = (size_t)NB_CNT * M_ROWS * 4;     //   4,866,048
    const size_t off_wbf  = 0;
    const size_t off_hbf  = off_wbf + wbf_bytes;
    const size_t off_pmax = off_hbf + hbf_bytes;
    const size_t off_psum = off_pmax + part_bytes;
    const size_t off_acc  = off_psum + part_bytes;
    const size_t need     = off_acc + 16;

    if (ws_size < need) {   // diagnosable failure: out = -12345
        sentinel<<<1, 1, 0, stream>>>(out);
        return;
    }

    unsigned short* wbf = (unsigned short*)((char*)d_ws + off_wbf);
    unsigned short* hbf = (unsigned short*)((char*)d_ws + off_hbf);
    float* pmax = (float*)((char*)d_ws + off_pmax);
    float* psum = (float*)((char*)d_ws + off_psum);
    float* accum = (float*)((char*)d_ws + off_acc);

    zero_acc<<<1, 64, 0, stream>>>(accum);

    long w4  = (long)V_SIZE * H_SIZE / 4;
    long w4p = (long)V_PAD * H_SIZE / 4;
    cvt_weight<<<2048, 256, 0, stream>>>((const float4*)wt, (ushort4*)wbf, w4, w4p);
    cvt_hidden<<<1024, 256, 0, stream>>>((const float4*)hid, (ushort4*)hbf);

    gemm_lse<<<NBLK, 512, 0, stream>>>(hbf, wbf, pmax, psum);

    reduce_rows<<<M_REAL, 256, 0, stream>>>(hid, labels, wt, pmax, psum, accum);
    finalize<<<1, 1, 0, stream>>>(accum, out);
}

// Round 4
// 2350.038 us; speedup vs baseline: 1.0302x; 1.0302x over previous
//
#include <hip/hip_runtime.h>
#include <hip/hip_bf16.h>
#include <math.h>

// ---------------------------------------------------------------------------
// Fused linear cross-entropy:  hidden(2047x2048) @ W^T(151936x2048) -> LSE - tgt
// Round 4: 256x256 tile, BK=32, 4-slot LDS ring, ONE barrier + 32 MFMA per
// K-step, counted vmcnt(8) (T4 — never 0 mid-loop), setprio (T5), XCD swizzle
// (T1). 64B LDS rows are naturally bank-conflict-free (no swizzle needed).
// ---------------------------------------------------------------------------

#define V_SIZE   151936
#define V_PAD    152064    // 594 * 256
#define H_SIZE   2048
#define M_ROWS   2048      // 2047 real rows + 1 zero pad row
#define M_REAL   2047
#define NB_CNT   594       // 152064 / 256
#define BM 256
#define BN 256
#define BK 32
#define KSTEPS   (H_SIZE / BK)   // 64
#define NBLK (8 * NB_CNT)        // 4752 blocks, divisible by 8
#define IGNORE_INDEX (-100)

typedef short bf16x8 __attribute__((ext_vector_type(8)));
typedef float floatx4 __attribute__((ext_vector_type(4)));

__device__ __forceinline__ unsigned short f2bf_rne(float f) {
    union { float f; unsigned u; } x; x.f = f;
    unsigned r = (x.u + 0x7fffu + ((x.u >> 16) & 1u)) >> 16;
    return (unsigned short)r;
}

__device__ __forceinline__ void gload16(const void* g, void* l) {
    __builtin_amdgcn_global_load_lds(
        (const __attribute__((address_space(1))) unsigned int*)g,
        (__attribute__((address_space(3))) unsigned int*)l, 16, 0, 0);
}

// ---- conversion kernels ----------------------------------------------------

__global__ void cvt_weight(const float4* __restrict__ in,
                           ushort4* __restrict__ out, long n4real, long n4pad) {
    long i = (long)blockIdx.x * blockDim.x + threadIdx.x;
    long stride = (long)gridDim.x * blockDim.x;
    for (; i < n4pad; i += stride) {
        ushort4 o;
        if (i < n4real) {
            float4 v = in[i];
            o.x = f2bf_rne(v.x); o.y = f2bf_rne(v.y);
            o.z = f2bf_rne(v.z); o.w = f2bf_rne(v.w);
        } else {
            o.x = 0; o.y = 0; o.z = 0; o.w = 0;
        }
        out[i] = o;
    }
}

__global__ void cvt_hidden(const float4* __restrict__ in,
                           ushort4* __restrict__ out) {
    const long n4 = (long)M_ROWS * H_SIZE / 4;
    const long valid4 = (long)M_REAL * H_SIZE / 4;
    long i = (long)blockIdx.x * blockDim.x + threadIdx.x;
    long stride = (long)gridDim.x * blockDim.x;
    for (; i < n4; i += stride) {
        ushort4 o;
        if (i < valid4) {
            float4 v = in[i];
            o.x = f2bf_rne(v.x); o.y = f2bf_rne(v.y);
            o.z = f2bf_rne(v.z); o.w = f2bf_rne(v.w);
        } else {
            o.x = 0; o.y = 0; o.z = 0; o.w = 0;
        }
        out[i] = o;
    }
}

// ---- main GEMM + per-tile online-LSE epilogue ------------------------------
// 512 threads (8 waves, 2M x 4N). Per-wave output 128x64 = acc[8][4].
// Ring of 4 slots, each one BK=32 K-step: A[256][32] + B[256][32] bf16 = 32KB.
// Per K-step: stage slot (k+3)&3, 12 ds_read_b128, lgkmcnt(0), 32 MFMA,
// vmcnt(8), ONE barrier. Slot being staged was fully read at step k-1.

__global__ __launch_bounds__(512, 2) void gemm_lse(
    const unsigned short* __restrict__ hbf,   // [2048][2048]
    const unsigned short* __restrict__ wbf,   // [152064][2048] (padded)
    float* __restrict__ pmax,                 // [594][2048]
    float* __restrict__ psum) {               // [594][2048]
    __shared__ short ring[4][16384];          // slot: A at 0, B at 8192 (shorts)
    __shared__ float eM[BM][4];
    __shared__ float eS[BM][4];

    const int t    = threadIdx.x;
    const int lane = t & 63;
    const int w    = t >> 6;
    const int wm   = w >> 2;          // 0..1 -> 128-row half
    const int wn   = w & 3;           // 0..3 -> 64-col slab
    const int fr   = lane & 15;
    const int fq   = lane >> 4;       // 0..3 -> 16B k-chunk

    // XCD-bijective remap: 4752 = 8 * 594; m fast (8 m-blocks share W slab)
    const int b    = blockIdx.x;
    const int lin  = (b & 7) * (NBLK / 8) + (b >> 3);
    const int mb   = lin & 7;
    const int nb   = lin >> 3;
    const int m0   = mb * BM;
    const int n0   = nb * BN;

    // staging: thread t -> row (t>>2), 16B chunk (t&3); LDS dest byte = t*16
    // (wave-linear as global_load_lds requires); second issue adds 128 rows.
    const int srow = t >> 2;
    const int sch  = (t & 3) * 8;    // shorts
    const unsigned short* gA0 = hbf + (size_t)(m0 + srow) * H_SIZE + sch;
    const unsigned short* gA1 = gA0 + (size_t)128 * H_SIZE;
    const unsigned short* gB0 = wbf + (size_t)(n0 + srow) * H_SIZE + sch;
    const unsigned short* gB1 = gB0 + (size_t)128 * H_SIZE;

    floatx4 zero4 = {0.f, 0.f, 0.f, 0.f};
    floatx4 acc[8][4];
#pragma unroll
    for (int i = 0; i < 8; ++i)
#pragma unroll
        for (int j = 0; j < 4; ++j) acc[i][j] = zero4;

    // ---- prologue: stage K-steps 0,1,2 into slots 0,1,2 (12 loads) ----
#pragma unroll
    for (int p = 0; p < 3; ++p) {
        short* sb = &ring[p][0];
        gload16(gA0 + p * 32, sb + t * 8);
        gload16(gA1 + p * 32, sb + 4096 + t * 8);
        gload16(gB0 + p * 32, sb + 8192 + t * 8);
        gload16(gB1 + p * 32, sb + 12288 + t * 8);
    }
    asm volatile("s_waitcnt vmcnt(8)" ::: "memory");   // slot 0 landed
    __builtin_amdgcn_s_barrier();
    asm volatile("" ::: "memory");

    for (int k = 0; k < KSTEPS; ++k) {
        // stage K-step k+3 into slot (k+3)&3 (last read at step k-1)
        if (k <= KSTEPS - 4) {
            short* sb = &ring[(k + 3) & 3][0];
            const int ko = (k + 3) * 32;
            gload16(gA0 + ko, sb + t * 8);
            gload16(gA1 + ko, sb + 4096 + t * 8);
            gload16(gB0 + ko, sb + 8192 + t * 8);
            gload16(gB1 + ko, sb + 12288 + t * 8);
        }

        const short* cb = &ring[k & 3][0];
        const short* pA = cb + (wm * 128 + fr) * 32 + fq * 8;
        const short* pB = cb + 8192 + (wn * 64 + fr) * 32 + fq * 8;
        bf16x8 af[8], bfv[4];
#pragma unroll
        for (int i = 0; i < 8; ++i)
            af[i] = *(const bf16x8*)(pA + i * 512);   // +16 rows = 512 shorts
#pragma unroll
        for (int j = 0; j < 4; ++j)
            bfv[j] = *(const bf16x8*)(pB + j * 512);

        asm volatile("s_waitcnt lgkmcnt(0)" ::: "memory");
        __builtin_amdgcn_sched_barrier(0);
        __builtin_amdgcn_s_setprio(1);
#pragma unroll
        for (int j = 0; j < 4; ++j)
#pragma unroll
            for (int i = 0; i < 8; ++i)
                acc[i][j] = __builtin_amdgcn_mfma_f32_16x16x32_bf16(
                    af[i], bfv[j], acc[i][j], 0, 0, 0);
        __builtin_amdgcn_s_setprio(0);
        __builtin_amdgcn_sched_barrier(0);

        // counted drain: keep K-steps k+2,k+3 (8 loads) in flight
        if (k <= KSTEPS - 4) {
            asm volatile("s_waitcnt vmcnt(8)" ::: "memory");
        } else if (k == KSTEPS - 3) {
            asm volatile("s_waitcnt vmcnt(4)" ::: "memory");
        } else if (k == KSTEPS - 2) {
            asm volatile("s_waitcnt vmcnt(0)" ::: "memory");
        }
        asm volatile("" ::: "memory");
        __builtin_amdgcn_s_barrier();
        asm volatile("" ::: "memory");
    }

    // ---- epilogue: per-row max + sum(exp) over 256 cols, masked past V ----
    // C/D layout: col = fr, row-in-frag = fq*4 + r.
    const int c0 = n0 + wn * 64 + fr;
#pragma unroll
    for (int m = 0; m < 8; ++m) {
#pragma unroll
        for (int r = 0; r < 4; ++r) {
            float v = -INFINITY;
#pragma unroll
            for (int n = 0; n < 4; ++n)
                if (c0 + n * 16 < V_SIZE) v = fmaxf(v, acc[m][n][r]);
            for (int off = 1; off < 16; off <<= 1)
                v = fmaxf(v, __shfl_xor(v, off, 64));
            float s = 0.f;
#pragma unroll
            for (int n = 0; n < 4; ++n)
                if (c0 + n * 16 < V_SIZE) s += expf(acc[m][n][r] - v);
            for (int off = 1; off < 16; off <<= 1)
                s += __shfl_xor(s, off, 64);
            if (fr == 0) {
                int row = wm * 128 + m * 16 + fq * 4 + r;
                eM[row][wn] = v;
                eS[row][wn] = s;
            }
        }
    }
    __syncthreads();
    if (t < BM) {
        float Mx = eM[t][0];
        for (int i = 1; i < 4; ++i) Mx = fmaxf(Mx, eM[t][i]);
        float Sx = 0.f;
        for (int i = 0; i < 4; ++i) {
            float d = eM[t][i] - Mx;   // -inf - finite -> -inf, exp -> 0
            Sx += eS[t][i] * expf(d);
        }
        size_t grow = (size_t)m0 + t;
        pmax[(size_t)nb * M_ROWS + grow] = Mx;
        psum[(size_t)nb * M_ROWS + grow] = Sx;
    }
}

// ---- per-row reduction: combine partials + exact fp32 target dot -----------

__global__ void zero_acc(float* a) {
    if (threadIdx.x < 2) a[threadIdx.x] = 0.f;
}

__global__ __launch_bounds__(256) void reduce_rows(
    const float* __restrict__ hid,
    const int* __restrict__ labels,
    const float* __restrict__ wt,
    const float* __restrict__ pmax,
    const float* __restrict__ psum,
    float* __restrict__ accum) {
    const int m = blockIdx.x;           // 0..2046
    const int t = threadIdx.x;
    const int lbl = labels[m + 1];
    const bool valid = (lbl != IGNORE_INDEX);

    float dot = 0.f;
    if (valid) {
        int li = lbl < 0 ? 0 : lbl;
        const float4* hr = (const float4*)(hid + (size_t)m * H_SIZE);
        const float4* wr = (const float4*)(wt + (size_t)li * H_SIZE);
#pragma unroll
        for (int i = 0; i < 2; ++i) {
            float4 a = hr[t + i * 256];
            float4 b = wr[t + i * 256];
            dot += a.x * b.x + a.y * b.y + a.z * b.z + a.w * b.w;
        }
    }

    float M = -INFINITY, S = 0.f;
    for (int nbi = t; nbi < NB_CNT; nbi += 256) {
        float m2 = pmax[(size_t)nbi * M_ROWS + m];
        float s2 = psum[(size_t)nbi * M_ROWS + m];
        if (m2 > M) { S = S * expf(M - m2) + s2; M = m2; }
        else        { S += s2 * expf(m2 - M); }
    }
    for (int off = 1; off < 64; off <<= 1) {
        float M2 = __shfl_xor(M, off, 64);
        float S2 = __shfl_xor(S, off, 64);
        float nm = fmaxf(M, M2);
        S = S * expf(M - nm) + S2 * expf(M2 - nm);
        M = nm;
        dot += __shfl_xor(dot, off, 64);
    }
    __shared__ float rM[4], rS[4], rD[4];
    const int wv = t >> 6, lane = t & 63;
    if (lane == 0) { rM[wv] = M; rS[wv] = S; rD[wv] = dot; }
    __syncthreads();
    if (t == 0) {
        float Mx = rM[0], Sx = rS[0], D = rD[0];
        for (int i = 1; i < 4; ++i) {
            float nm = fmaxf(Mx, rM[i]);
            Sx = Sx * expf(Mx - nm) + rS[i] * expf(rM[i] - nm);
            Mx = nm;
            D += rD[i];
        }
        if (valid) {
            atomicAdd(&accum[0], (Mx + logf(Sx)) - D);
            atomicAdd(&accum[1], 1.0f);
        }
    }
}

__global__ void finalize(const float* __restrict__ accum, float* __restrict__ out) {
    out[0] = accum[0] / accum[1];
}

__global__ void sentinel(float* out) { out[0] = -12345.0f; }

// ---------------------------------------------------------------------------

extern "C" void kernel_launch(void* const* d_in, const int* in_sizes, int n_in,
                              void* d_out, int out_size, void* d_ws, size_t ws_size,
                              hipStream_t stream) {
    const float* hid    = (const float*)d_in[0];
    const int*   labels = (const int*)d_in[1];
    const float* wt     = (const float*)d_in[2];
    float* out = (float*)d_out;

    const size_t wbf_bytes  = (size_t)V_PAD * H_SIZE * 2;      // 622,854,144
    const size_t hbf_bytes  = (size_t)M_ROWS * H_SIZE * 2;     //   8,388,608
    const size_t part_bytes = (size_t)NB_CNT * M_ROWS * 4;     //   4,866,048
    const size_t off_wbf  = 0;
    const size_t off_hbf  = off_wbf + wbf_bytes;
    const size_t off_pmax = off_hbf + hbf_bytes;
    const size_t off_psum = off_pmax + part_bytes;
    const size_t off_acc  = off_psum + part_bytes;
    const size_t need     = off_acc + 16;

    if (ws_size < need) {   // diagnosable failure: out = -12345
        sentinel<<<1, 1, 0, stream>>>(out);
        return;
    }

    unsigned short* wbf = (unsigned short*)((char*)d_ws + off_wbf);
    unsigned short* hbf = (unsigned short*)((char*)d_ws + off_hbf);
    float* pmax = (float*)((char*)d_ws + off_pmax);
    float* psum = (float*)((char*)d_ws + off_psum);
    float* accum = (float*)((char*)d_ws + off_acc);

    zero_acc<<<1, 64, 0, stream>>>(accum);

    long w4  = (long)V_SIZE * H_SIZE / 4;
    long w4p = (long)V_PAD * H_SIZE / 4;
    cvt_weight<<<2048, 256, 0, stream>>>((const float4*)wt, (ushort4*)wbf, w4, w4p);
    cvt_hidden<<<1024, 256, 0, stream>>>((const float4*)hid, (ushort4*)hbf);

    gemm_lse<<<NBLK, 512, 0, stream>>>(hbf, wbf, pmax, psum);

    reduce_rows<<<M_REAL, 256, 0, stream>>>(hid, labels, wt, pmax, psum, accum);
    finalize<<<1, 1, 0, stream>>>(accum, out);
}

// Round 5
// 2107.556 us; speedup vs baseline: 1.1487x; 1.1151x over previous
//
#include <hip/hip_runtime.h>
#include <hip/hip_bf16.h>
#include <math.h>

// ---------------------------------------------------------------------------
// Fused linear cross-entropy:  hidden(2047x2048) @ W^T(151936x2048) -> LSE - tgt
// Round 5: m201-style 8-phase port. 256x256 tile, BK=64, 2 LDS buffers,
// 8 waves (2Mx4N), 4 phases/K-tile x 16 MFMA, stage whole next K-tile at
// phase 0, vmcnt(0) 3 phases later (T4 principle), T2 swizzle, T5 setprio,
// T1 XCD-bijective block swizzle. Raw s_barrier (no vmcnt drain per phase).
// ---------------------------------------------------------------------------

#define V_SIZE   151936
#define V_PAD    152064    // 594 * 256
#define H_SIZE   2048
#define M_ROWS   2048      // 2047 real rows + 1 zero pad row
#define M_REAL   2047
#define NB_CNT   594       // 152064 / 256
#define BM 256
#define BN 256
#define BK 64
#define KTILES   (H_SIZE / BK)   // 32
#define NBLK (8 * NB_CNT)        // 4752 blocks, divisible by 8
#define IGNORE_INDEX (-100)

typedef short bf16x8 __attribute__((ext_vector_type(8)));
typedef float floatx4 __attribute__((ext_vector_type(4)));

__device__ __forceinline__ unsigned short f2bf_rne(float f) {
    union { float f; unsigned u; } x; x.f = f;
    unsigned r = (x.u + 0x7fffu + ((x.u >> 16) & 1u)) >> 16;
    return (unsigned short)r;
}

__device__ __forceinline__ void gload16(const void* g, void* l) {
    __builtin_amdgcn_global_load_lds(
        (const __attribute__((address_space(1))) unsigned int*)g,
        (__attribute__((address_space(3))) unsigned int*)l, 16, 0, 0);
}

// ---- conversion kernels ----------------------------------------------------

__global__ void cvt_weight(const float4* __restrict__ in,
                           ushort4* __restrict__ out, long n4real, long n4pad) {
    long i = (long)blockIdx.x * blockDim.x + threadIdx.x;
    long stride = (long)gridDim.x * blockDim.x;
    for (; i < n4pad; i += stride) {
        ushort4 o;
        if (i < n4real) {
            float4 v = in[i];
            o.x = f2bf_rne(v.x); o.y = f2bf_rne(v.y);
            o.z = f2bf_rne(v.z); o.w = f2bf_rne(v.w);
        } else {
            o.x = 0; o.y = 0; o.z = 0; o.w = 0;
        }
        out[i] = o;
    }
}

__global__ void cvt_hidden(const float4* __restrict__ in,
                           ushort4* __restrict__ out) {
    const long n4 = (long)M_ROWS * H_SIZE / 4;
    const long valid4 = (long)M_REAL * H_SIZE / 4;
    long i = (long)blockIdx.x * blockDim.x + threadIdx.x;
    long stride = (long)gridDim.x * blockDim.x;
    for (; i < n4; i += stride) {
        ushort4 o;
        if (i < valid4) {
            float4 v = in[i];
            o.x = f2bf_rne(v.x); o.y = f2bf_rne(v.y);
            o.z = f2bf_rne(v.z); o.w = f2bf_rne(v.w);
        } else {
            o.x = 0; o.y = 0; o.z = 0; o.w = 0;
        }
        out[i] = o;
    }
}

// ---- main GEMM + per-tile online-LSE epilogue ------------------------------
// 512 threads = 8 waves (wm 0..1, wn 0..3); per-wave output 128x64 = acc[8][4].
// LDS: A[2][256][64] + B[2][256][64] bf16 (128KB) + eM/eS (8KB).
// K-tile j, 4 phases:
//   P0: ds A-quarter0(8) + B-half0(4); STAGE K-tile j+1 (8 gloads) -> buf^1;
//       bar; lgkm0; 16 MFMA (m-half0, n-half0); bar.
//   P1: ds A-quarter1(8);  bar; lgkm0; MFMA (1,0); bar.
//   P2: ds B-half1(4);     bar; lgkm0; MFMA (1,1); bar.
//   P3: ds A-quarter0(8);  bar; lgkm0; MFMA (0,1); vmcnt(0) [stage issued
//       3 phases ago -> latency covered]; bar.

__global__ __launch_bounds__(512, 2) void gemm_lse(
    const unsigned short* __restrict__ hbf,   // [2048][2048]
    const unsigned short* __restrict__ wbf,   // [152064][2048] (padded)
    float* __restrict__ pmax,                 // [594][2048]
    float* __restrict__ psum) {               // [594][2048]
    __shared__ short ldsA[2][16384];          // [buf][256 rows][64 k] swizzled
    __shared__ short ldsB[2][16384];
    __shared__ float eM[BM][4];
    __shared__ float eS[BM][4];

    const int t    = threadIdx.x;
    const int lane = t & 63;
    const int w    = t >> 6;
    const int wm   = w >> 2;          // 0..1 -> 128-row half (A-half = wm, fixed)
    const int wn   = w & 3;           // 0..3 -> 64-col slab (B-half = wn>>1, fixed)
    const int fr   = lane & 15;
    const int fq   = lane >> 4;       // 0..3
    const int fsw  = fr & 7;          // read-side swizzle (row&7 == fr&7)

    // T1: XCD-bijective remap (4752 = 8 * 594), m fast for W-slab L2 reuse
    const int b    = blockIdx.x;
    const int lin  = (b & 7) * (NBLK / 8) + (b >> 3);
    const int mb   = lin & 7;
    const int nb   = lin >> 3;
    const int m0   = mb * BM;
    const int n0   = nb * BN;

    // staging: thread t -> row (t>>3), phys chunk (t&7); global logical chunk
    // pre-swizzled: (t&7)^(row&7) (T2, rule 21). Issues add 64 rows (&7 inv).
    const int srow   = t >> 3;
    const int schunk = (t & 7) ^ (srow & 7);
    const unsigned short* gA = hbf + (size_t)(m0 + srow) * H_SIZE + schunk * 8;
    const unsigned short* gB = wbf + (size_t)(n0 + srow) * H_SIZE + schunk * 8;

#define STAGE(bufi, kt) do {                                          \
        const size_t _ko = (size_t)(kt) * 64;                         \
        short* _a = &ldsA[bufi][0];                                   \
        short* _b = &ldsB[bufi][0];                                   \
        gload16(gA + _ko,                        _a + t * 8);         \
        gload16(gA + (size_t)64  * H_SIZE + _ko, _a + 4096  + t * 8); \
        gload16(gA + (size_t)128 * H_SIZE + _ko, _a + 8192  + t * 8); \
        gload16(gA + (size_t)192 * H_SIZE + _ko, _a + 12288 + t * 8); \
        gload16(gB + _ko,                        _b + t * 8);         \
        gload16(gB + (size_t)64  * H_SIZE + _ko, _b + 4096  + t * 8); \
        gload16(gB + (size_t)128 * H_SIZE + _ko, _b + 8192  + t * 8); \
        gload16(gB + (size_t)192 * H_SIZE + _ko, _b + 12288 + t * 8); \
    } while (0)

    floatx4 zero4 = {0.f, 0.f, 0.f, 0.f};
    floatx4 acc[8][4];
#pragma unroll
    for (int i = 0; i < 8; ++i)
#pragma unroll
        for (int j = 0; j < 4; ++j) acc[i][j] = zero4;

    bf16x8 af[4][2], bfv[2][2];

#define DSA(MH) do {                                                        \
        _Pragma("unroll") for (int i2 = 0; i2 < 4; ++i2)                    \
        _Pragma("unroll") for (int kk = 0; kk < 2; ++kk)                    \
            af[i2][kk] = *(const bf16x8*)(bA                                \
                + (size_t)(wm * 128 + (MH) * 64 + i2 * 16 + fr) * 64        \
                + (((kk * 4 + fq) ^ fsw) * 8));                             \
    } while (0)
#define DSB(NH) do {                                                        \
        _Pragma("unroll") for (int j2 = 0; j2 < 2; ++j2)                    \
        _Pragma("unroll") for (int kk = 0; kk < 2; ++kk)                    \
            bfv[j2][kk] = *(const bf16x8*)(bB                               \
                + (size_t)(wn * 64 + (NH) * 32 + j2 * 16 + fr) * 64         \
                + (((kk * 4 + fq) ^ fsw) * 8));                             \
    } while (0)
#define MFMAQ(MH, NH) do {                                                  \
        _Pragma("unroll") for (int kk = 0; kk < 2; ++kk)                    \
        _Pragma("unroll") for (int i2 = 0; i2 < 4; ++i2)                    \
        _Pragma("unroll") for (int j2 = 0; j2 < 2; ++j2)                    \
            acc[(MH)*4 + i2][(NH)*2 + j2] =                                 \
                __builtin_amdgcn_mfma_f32_16x16x32_bf16(                    \
                    af[i2][kk], bfv[j2][kk],                                \
                    acc[(MH)*4 + i2][(NH)*2 + j2], 0, 0, 0);                \
    } while (0)
#define PH_BEGIN() do {                                                     \
        asm volatile("" ::: "memory");                                      \
        __builtin_amdgcn_s_barrier();                                       \
        asm volatile("s_waitcnt lgkmcnt(0)" ::: "memory");                  \
        __builtin_amdgcn_sched_barrier(0);                                  \
        __builtin_amdgcn_s_setprio(1);                                      \
    } while (0)
#define PH_END() do {                                                       \
        __builtin_amdgcn_s_setprio(0);                                      \
        __builtin_amdgcn_sched_barrier(0);                                  \
        asm volatile("" ::: "memory");                                      \
        __builtin_amdgcn_s_barrier();                                       \
        asm volatile("" ::: "memory");                                      \
    } while (0)

    // ---- prologue: stage K-tile 0 into buf 0 ----
    STAGE(0, 0);
    asm volatile("s_waitcnt vmcnt(0)" ::: "memory");
    __builtin_amdgcn_s_barrier();
    asm volatile("" ::: "memory");

    for (int j = 0; j < KTILES; ++j) {
        const short* bA = &ldsA[j & 1][0];
        const short* bB = &ldsB[j & 1][0];
        // ---- P0 ----
        DSA(0); DSB(0);
        if (j < KTILES - 1) STAGE((j & 1) ^ 1, j + 1);
        asm volatile("s_waitcnt lgkmcnt(8)" ::: "memory");
        PH_BEGIN(); MFMAQ(0, 0); PH_END();
        // ---- P1 ----
        DSA(1);
        PH_BEGIN(); MFMAQ(1, 0); PH_END();
        // ---- P2 ----
        DSB(1);
        PH_BEGIN(); MFMAQ(1, 1); PH_END();
        // ---- P3 ----
        DSA(0);
        PH_BEGIN(); MFMAQ(0, 1);
        __builtin_amdgcn_s_setprio(0);
        __builtin_amdgcn_sched_barrier(0);
        if (j < KTILES - 1)
            asm volatile("s_waitcnt vmcnt(0)" ::: "memory");  // issued 3 phases ago
        asm volatile("" ::: "memory");
        __builtin_amdgcn_s_barrier();
        asm volatile("" ::: "memory");
    }

    // ---- epilogue: per-row max + sum(exp) over 256 cols, masked past V ----
    // C/D layout: col = fr, row-in-frag = fq*4 + r.
    const int c0 = n0 + wn * 64 + fr;
#pragma unroll
    for (int m = 0; m < 8; ++m) {
#pragma unroll
        for (int r = 0; r < 4; ++r) {
            float v = -INFINITY;
#pragma unroll
            for (int n = 0; n < 4; ++n)
                if (c0 + n * 16 < V_SIZE) v = fmaxf(v, acc[m][n][r]);
            for (int off = 1; off < 16; off <<= 1)
                v = fmaxf(v, __shfl_xor(v, off, 64));
            float s = 0.f;
#pragma unroll
            for (int n = 0; n < 4; ++n)
                if (c0 + n * 16 < V_SIZE) s += expf(acc[m][n][r] - v);
            for (int off = 1; off < 16; off <<= 1)
                s += __shfl_xor(s, off, 64);
            if (fr == 0) {
                int row = wm * 128 + m * 16 + fq * 4 + r;
                eM[row][wn] = v;
                eS[row][wn] = s;
            }
        }
    }
    __syncthreads();
    if (t < BM) {
        float Mx = eM[t][0];
        for (int i = 1; i < 4; ++i) Mx = fmaxf(Mx, eM[t][i]);
        float Sx = 0.f;
        for (int i = 0; i < 4; ++i) {
            float d = eM[t][i] - Mx;   // -inf - finite -> -inf, exp -> 0
            Sx += eS[t][i] * expf(d);
        }
        size_t grow = (size_t)m0 + t;
        pmax[(size_t)nb * M_ROWS + grow] = Mx;
        psum[(size_t)nb * M_ROWS + grow] = Sx;
    }
}

// ---- per-row reduction: combine partials + exact fp32 target dot -----------

__global__ void zero_acc(float* a) {
    if (threadIdx.x < 2) a[threadIdx.x] = 0.f;
}

__global__ __launch_bounds__(256) void reduce_rows(
    const float* __restrict__ hid,
    const int* __restrict__ labels,
    const float* __restrict__ wt,
    const float* __restrict__ pmax,
    const float* __restrict__ psum,
    float* __restrict__ accum) {
    const int m = blockIdx.x;           // 0..2046
    const int t = threadIdx.x;
    const int lbl = labels[m + 1];
    const bool valid = (lbl != IGNORE_INDEX);

    float dot = 0.f;
    if (valid) {
        int li = lbl < 0 ? 0 : lbl;
        const float4* hr = (const float4*)(hid + (size_t)m * H_SIZE);
        const float4* wr = (const float4*)(wt + (size_t)li * H_SIZE);
#pragma unroll
        for (int i = 0; i < 2; ++i) {
            float4 a = hr[t + i * 256];
            float4 b = wr[t + i * 256];
            dot += a.x * b.x + a.y * b.y + a.z * b.z + a.w * b.w;
        }
    }

    float M = -INFINITY, S = 0.f;
    for (int nbi = t; nbi < NB_CNT; nbi += 256) {
        float m2 = pmax[(size_t)nbi * M_ROWS + m];
        float s2 = psum[(size_t)nbi * M_ROWS + m];
        if (m2 > M) { S = S * expf(M - m2) + s2; M = m2; }
        else        { S += s2 * expf(m2 - M); }
    }
    for (int off = 1; off < 64; off <<= 1) {
        float M2 = __shfl_xor(M, off, 64);
        float S2 = __shfl_xor(S, off, 64);
        float nm = fmaxf(M, M2);
        S = S * expf(M - nm) + S2 * expf(M2 - nm);
        M = nm;
        dot += __shfl_xor(dot, off, 64);
    }
    __shared__ float rM[4], rS[4], rD[4];
    const int wv = t >> 6, lane = t & 63;
    if (lane == 0) { rM[wv] = M; rS[wv] = S; rD[wv] = dot; }
    __syncthreads();
    if (t == 0) {
        float Mx = rM[0], Sx = rS[0], D = rD[0];
        for (int i = 1; i < 4; ++i) {
            float nm = fmaxf(Mx, rM[i]);
            Sx = Sx * expf(Mx - nm) + rS[i] * expf(rM[i] - nm);
            Mx = nm;
            D += rD[i];
        }
        if (valid) {
            atomicAdd(&accum[0], (Mx + logf(Sx)) - D);
            atomicAdd(&accum[1], 1.0f);
        }
    }
}

__global__ void finalize(const float* __restrict__ accum, float* __restrict__ out) {
    out[0] = accum[0] / accum[1];
}

__global__ void sentinel(float* out) { out[0] = -12345.0f; }

// ---------------------------------------------------------------------------

extern "C" void kernel_launch(void* const* d_in, const int* in_sizes, int n_in,
                              void* d_out, int out_size, void* d_ws, size_t ws_size,
                              hipStream_t stream) {
    const float* hid    = (const float*)d_in[0];
    const int*   labels = (const int*)d_in[1];
    const float* wt     = (const float*)d_in[2];
    float* out = (float*)d_out;

    const size_t wbf_bytes  = (size_t)V_PAD * H_SIZE * 2;      // 622,854,144
    const size_t hbf_bytes  = (size_t)M_ROWS * H_SIZE * 2;     //   8,388,608
    const size_t part_bytes = (size_t)NB_CNT * M_ROWS * 4;     //   4,866,048
    const size_t off_wbf  = 0;
    const size_t off_hbf  = off_wbf + wbf_bytes;
    const size_t off_pmax = off_hbf + hbf_bytes;
    const size_t off_psum = off_pmax + part_bytes;
    const size_t off_acc  = off_psum + part_bytes;
    const size_t need     = off_acc + 16;

    if (ws_size < need) {   // diagnosable failure: out = -12345
        sentinel<<<1, 1, 0, stream>>>(out);
        return;
    }

    unsigned short* wbf = (unsigned short*)((char*)d_ws + off_wbf);
    unsigned short* hbf = (unsigned short*)((char*)d_ws + off_hbf);
    float* pmax = (float*)((char*)d_ws + off_pmax);
    float* psum = (float*)((char*)d_ws + off_psum);
    float* accum = (float*)((char*)d_ws + off_acc);

    zero_acc<<<1, 64, 0, stream>>>(accum);

    long w4  = (long)V_SIZE * H_SIZE / 4;
    long w4p = (long)V_PAD * H_SIZE / 4;
    cvt_weight<<<2048, 256, 0, stream>>>((const float4*)wt, (ushort4*)wbf, w4, w4p);
    cvt_hidden<<<1024, 256, 0, stream>>>((const float4*)hid, (ushort4*)hbf);

    gemm_lse<<<NBLK, 512, 0, stream>>>(hbf, wbf, pmax, psum);

    reduce_rows<<<M_REAL, 256, 0, stream>>>(hid, labels, wt, pmax, psum, accum);
    finalize<<<1, 1, 0, stream>>>(accum, out);
}